// Round 1
// baseline (860.199 us; speedup 1.0000x reference)
//
#include <hip/hip_runtime.h>

typedef short bf16x8 __attribute__((ext_vector_type(8)));
typedef float f32x4  __attribute__((ext_vector_type(4)));

#define AS1 __attribute__((address_space(1)))
#define AS3 __attribute__((address_space(3)))

__device__ __forceinline__ void gload16(const void* g, void* l) {
  __builtin_amdgcn_global_load_lds((const AS1 void*)g, (AS3 void*)l, 16, 0, 0);
}

__device__ __forceinline__ short f2bf(float f) {
  union { float fv; unsigned u; } v; v.fv = f;
  unsigned r = v.u + 0x7fffu + ((v.u >> 16) & 1u);
  return (short)(r >> 16);
}

// ---------------- cast x (fp32 -> bf16), 4 elems/thread ----------------
__global__ void cast_x_kernel(const float* __restrict__ x, short* __restrict__ xb, long n4) {
  long i = (long)blockIdx.x * 256 + threadIdx.x;
  if (i < n4) {
    float4 v = ((const float4*)x)[i];
    short4 s;
    s.x = f2bf(v.x); s.y = f2bf(v.y); s.z = f2bf(v.z); s.w = f2bf(v.w);
    ((short4*)xb)[i] = s;
  }
}

// ---------------- weight prep ----------------
// LT[i*128+r][c] = bf16(left_w[i][r][c])                  (1,048,576 elems)
// WT[(i*16+n)*128+e][d]      = bf16(diag[i][n][d][e])  d<128
// WT[(i*16+n)*128+e][128+r'] = bf16(right_w[i][n*128+e][r'])   (2,097,152 elems)
__global__ void prep_kernel(const float* __restrict__ left_w, const float* __restrict__ diag,
                            const float* __restrict__ right_w,
                            short* __restrict__ LT, short* __restrict__ WT) {
  long idx = (long)blockIdx.x * 256 + threadIdx.x;
  const long LTN = 4L * 128 * 2048;
  const long WTN = 4L * 16 * 128 * 256;
  if (idx < LTN) {
    LT[idx] = f2bf(left_w[idx]);
  } else if (idx < LTN + WTN) {
    long j = idx - LTN;
    int d = (int)(j & 255);
    long rest = j >> 8;          // gi*128 + e
    int e = (int)(rest & 127);
    long gi = rest >> 7;         // i*16 + n
    int i = (int)(gi >> 4), n = (int)(gi & 15);
    float v;
    if (d < 128) v = diag[(gi * 128 + d) * 128 + e];
    else         v = right_w[((long)i * 2048 + n * 128 + e) * 128 + (d - 128)];
    WT[j] = f2bf(v);
  }
}

// ---------------- generic 128x128-tile GEMM: C[M][N](bf16) = A[M][K] @ BT[N][K]^T ----------------
__global__ __launch_bounds__(256) void gemm_bt(const short* __restrict__ A, const short* __restrict__ BT,
                                               short* __restrict__ C, int M, int N, int K) {
  __shared__ __align__(16) short As[128 * 64];
  __shared__ __align__(16) short Bs[128 * 64];
  int tid = threadIdx.x, w = tid >> 6, lane = tid & 63;
  int m0 = blockIdx.x * 128, n0 = blockIdx.y * 128;
  int wm = (w >> 1) * 64, wn = (w & 1) * 64;
  int quad = lane >> 4, l16 = lane & 15;
  int srow = lane >> 3, scol = (lane & 7) * 8;
  f32x4 acc[4][4] = {};
  for (int k0 = 0; k0 < K; k0 += 64) {
    for (int p = 0; p < 4; ++p) {
      int r = p * 32 + w * 8 + srow;
      gload16(&A[(long)(m0 + r) * K + k0 + scol], &As[(p * 32 + w * 8) * 64]);
      gload16(&BT[(long)(n0 + r) * K + k0 + scol], &Bs[(p * 32 + w * 8) * 64]);
    }
    __syncthreads();
#pragma unroll
    for (int kk = 0; kk < 2; ++kk) {
      bf16x8 a[4], b[4];
#pragma unroll
      for (int t = 0; t < 4; ++t) a[t] = *(const bf16x8*)&As[(wm + t * 16 + l16) * 64 + kk * 32 + quad * 8];
#pragma unroll
      for (int t = 0; t < 4; ++t) b[t] = *(const bf16x8*)&Bs[(wn + t * 16 + l16) * 64 + kk * 32 + quad * 8];
#pragma unroll
      for (int mt = 0; mt < 4; ++mt)
#pragma unroll
        for (int nt = 0; nt < 4; ++nt)
          acc[mt][nt] = __builtin_amdgcn_mfma_f32_16x16x32_bf16(a[mt], b[nt], acc[mt][nt], 0, 0, 0);
    }
    __syncthreads();
  }
#pragma unroll
  for (int mt = 0; mt < 4; ++mt)
#pragma unroll
    for (int nt = 0; nt < 4; ++nt)
#pragma unroll
      for (int r = 0; r < 4; ++r) {
        int m = m0 + wm + mt * 16 + quad * 4 + r;
        int n = n0 + wn + nt * 16 + l16;
        C[(long)m * N + n] = f2bf(acc[mt][nt][r]);
      }
}

// ---------------- grouped lori GEMM: per (i,n): [128 tok x 256] @ WT[i][n]^T -> 128 out ch ----------------
// kt 0,1: A from tok (block n channels); kt 2,3: A from rnk (rank channels, col offset co)
__global__ __launch_bounds__(256) void lori_gemm(const short* __restrict__ tok, const short* __restrict__ rnk,
                                                 int rstride, const short* __restrict__ WT,
                                                 const float* __restrict__ rb, const float* __restrict__ bp,
                                                 int i_base, short* __restrict__ qb, short* __restrict__ kb,
                                                 short* __restrict__ vT, float* __restrict__ out) {
  __shared__ __align__(16) short As[128 * 64];
  __shared__ __align__(16) short Bs[128 * 64];
  int tid = threadIdx.x, w = tid >> 6, lane = tid & 63;
  int i = i_base + (blockIdx.y >> 4);
  int n = blockIdx.y & 15;
  int t0 = blockIdx.x * 128;
  int co = (i < 3) ? i * 128 : 0;
  const short* WTn = WT + (long)(i * 16 + n) * 128 * 256;
  int wm = (w >> 1) * 64, wn = (w & 1) * 64;
  int quad = lane >> 4, l16 = lane & 15;
  int srow = lane >> 3, scol = (lane & 7) * 8;
  f32x4 acc[4][4] = {};
#pragma unroll
  for (int kt = 0; kt < 4; ++kt) {
    for (int p = 0; p < 4; ++p) {
      int r = p * 32 + w * 8 + srow;
      const short* ga;
      if (kt < 2) ga = &tok[(long)(t0 + r) * 2048 + n * 128 + kt * 64 + scol];
      else        ga = &rnk[(long)(t0 + r) * rstride + co + (kt - 2) * 64 + scol];
      gload16(ga, &As[(p * 32 + w * 8) * 64]);
      gload16(&WTn[r * 256 + kt * 64 + scol], &Bs[(p * 32 + w * 8) * 64]);
    }
    __syncthreads();
#pragma unroll
    for (int kk = 0; kk < 2; ++kk) {
      bf16x8 a[4], b[4];
#pragma unroll
      for (int t = 0; t < 4; ++t) a[t] = *(const bf16x8*)&As[(wm + t * 16 + l16) * 64 + kk * 32 + quad * 8];
#pragma unroll
      for (int t = 0; t < 4; ++t) b[t] = *(const bf16x8*)&Bs[(wn + t * 16 + l16) * 64 + kk * 32 + quad * 8];
#pragma unroll
      for (int mt = 0; mt < 4; ++mt)
#pragma unroll
        for (int nt = 0; nt < 4; ++nt)
          acc[mt][nt] = __builtin_amdgcn_mfma_f32_16x16x32_bf16(a[mt], b[nt], acc[mt][nt], 0, 0, 0);
    }
    __syncthreads();
  }
  int b = t0 >> 11;
  int tl0 = t0 & 2047;
  const float QSC = 0.08838834764831845f * 1.4426950408889634f;  // 1/sqrt(128) * log2(e)
#pragma unroll
  for (int mt = 0; mt < 4; ++mt) {
#pragma unroll
    for (int nt = 0; nt < 4; ++nt) {
      int e = wn + nt * 16 + l16;
      int c = n * 128 + e;
      float bias = rb[i * 2048 + c] + bp[i * 2048 + c];
      int tl = tl0 + wm + mt * 16 + quad * 4;
      if (i == 0) {
#pragma unroll
        for (int r = 0; r < 4; ++r)
          qb[((long)(b * 16 + n) * 2048 + tl + r) * 128 + e] = f2bf((acc[mt][nt][r] + bias) * QSC);
      } else if (i == 1) {
#pragma unroll
        for (int r = 0; r < 4; ++r)
          kb[((long)(b * 16 + n) * 2048 + tl + r) * 128 + e] = f2bf(acc[mt][nt][r] + bias);
      } else if (i == 2) {
        short4 s4;
        s4.x = f2bf(acc[mt][nt][0] + bias);
        s4.y = f2bf(acc[mt][nt][1] + bias);
        s4.z = f2bf(acc[mt][nt][2] + bias);
        s4.w = f2bf(acc[mt][nt][3] + bias);
        *(short4*)&vT[((long)(b * 16 + n) * 128 + e) * 2048 + tl] = s4;
      } else {
#pragma unroll
        for (int r = 0; r < 4; ++r)
          out[(long)(t0 + wm + mt * 16 + quad * 4 + r) * 2048 + c] = acc[mt][nt][r] + bias;
      }
    }
  }
}

// ---------------- flash attention, causal. q pre-scaled by log2e/sqrt(hd). ----------------
// qb,kb: [b][h][t][d] bf16; vT: [b][h][d][t] bf16; y out: [b][t][h*128+d] bf16
__global__ __launch_bounds__(256) void attn_kernel(const short* __restrict__ qb, const short* __restrict__ kb,
                                                   const short* __restrict__ vT, short* __restrict__ y) {
  __shared__ __align__(16) short qs[64 * 128];
  __shared__ __align__(16) short ks[64 * 128];
  __shared__ __align__(16) short vs[128 * 64];
  __shared__ __align__(16) short ps[4 * 16 * 72];  // padded stride 72 to reduce bank conflicts
  int tid = threadIdx.x, w = tid >> 6, lane = tid & 63;
  int bh = blockIdx.y;          // b*16+h
  int b = bh >> 4, h = bh & 15;
  int qt = blockIdx.x;          // 64-row q tile
  int quad = lane >> 4, l16 = lane & 15;

  // stage Q tile
  for (int p = 0; p < 4; ++p) {
    int r = p * 16 + w * 4 + (lane >> 4);
    gload16(&qb[((long)bh * 2048 + qt * 64 + r) * 128 + l16 * 8], &qs[(p * 16 + w * 4) * 128]);
  }
  __syncthreads();
  bf16x8 aq[4];
#pragma unroll
  for (int kk = 0; kk < 4; ++kk) aq[kk] = *(const bf16x8*)&qs[(w * 16 + l16) * 128 + kk * 32 + quad * 8];

  f32x4 O[8] = {};
  float mst[4], lst[4];
#pragma unroll
  for (int r = 0; r < 4; ++r) { mst[r] = -3.0e38f; lst[r] = 0.f; }
  short* psw = &ps[w * 16 * 72];

  for (int jt = 0; jt <= qt; ++jt) {
    // stage K (64x128) and V^T (128x64)
    for (int p = 0; p < 4; ++p) {
      int r = p * 16 + w * 4 + (lane >> 4);
      gload16(&kb[((long)bh * 2048 + jt * 64 + r) * 128 + l16 * 8], &ks[(p * 16 + w * 4) * 128]);
      int r2 = p * 32 + w * 8 + (lane >> 3);
      gload16(&vT[((long)bh * 128 + r2) * 2048 + jt * 64 + (lane & 7) * 8], &vs[(p * 32 + w * 8) * 64]);
    }
    __syncthreads();

    // S = Q @ K^T  (wave: 16 rows x 64 keys)
    f32x4 s[4];
#pragma unroll
    for (int nt = 0; nt < 4; ++nt) {
      f32x4 a = {};
#pragma unroll
      for (int kk = 0; kk < 4; ++kk) {
        bf16x8 bk = *(const bf16x8*)&ks[(nt * 16 + l16) * 128 + kk * 32 + quad * 8];
        a = __builtin_amdgcn_mfma_f32_16x16x32_bf16(aq[kk], bk, a, 0, 0, 0);
      }
      s[nt] = a;
    }
    if (jt == qt) {
#pragma unroll
      for (int nt = 0; nt < 4; ++nt) {
        int key = nt * 16 + l16;
#pragma unroll
        for (int r = 0; r < 4; ++r) {
          int row = w * 16 + quad * 4 + r;
          if (key > row) s[nt][r] = -3.0e38f;
        }
      }
    }
    // online softmax (base-2 domain)
    float al[4];
#pragma unroll
    for (int r = 0; r < 4; ++r) {
      float mx = fmaxf(fmaxf(s[0][r], s[1][r]), fmaxf(s[2][r], s[3][r]));
#pragma unroll
      for (int off = 1; off < 16; off <<= 1) mx = fmaxf(mx, __shfl_xor(mx, off));
      float nm = fmaxf(mst[r], mx);
      al[r] = exp2f(mst[r] - nm);
      mst[r] = nm;
    }
#pragma unroll
    for (int r = 0; r < 4; ++r) {
      float sum = 0.f;
#pragma unroll
      for (int nt = 0; nt < 4; ++nt) {
        float p = exp2f(s[nt][r] - mst[r]);
        s[nt][r] = p;
        sum += p;
      }
#pragma unroll
      for (int off = 1; off < 16; off <<= 1) sum += __shfl_xor(sum, off);
      lst[r] = lst[r] * al[r] + sum;
    }
#pragma unroll
    for (int dt = 0; dt < 8; ++dt)
#pragma unroll
      for (int r = 0; r < 4; ++r) O[dt][r] *= al[r];
    // P: C-layout -> A-layout via LDS (per-wave region, no barrier needed)
#pragma unroll
    for (int nt = 0; nt < 4; ++nt)
#pragma unroll
      for (int r = 0; r < 4; ++r)
        psw[(quad * 4 + r) * 72 + nt * 16 + l16] = f2bf(s[nt][r]);
    // O += P @ V
#pragma unroll
    for (int kk = 0; kk < 2; ++kk) {
      bf16x8 ap = *(const bf16x8*)&psw[l16 * 72 + kk * 32 + quad * 8];
#pragma unroll
      for (int dt = 0; dt < 8; ++dt) {
        bf16x8 bv = *(const bf16x8*)&vs[(dt * 16 + l16) * 64 + kk * 32 + quad * 8];
        O[dt] = __builtin_amdgcn_mfma_f32_16x16x32_bf16(ap, bv, O[dt], 0, 0, 0);
      }
    }
    __syncthreads();
  }
  // epilogue: y[b][t][h*128+d] = O / l
  float inv[4];
#pragma unroll
  for (int r = 0; r < 4; ++r) inv[r] = 1.0f / lst[r];
#pragma unroll
  for (int dt = 0; dt < 8; ++dt)
#pragma unroll
    for (int r = 0; r < 4; ++r) {
      int t = qt * 64 + w * 16 + quad * 4 + r;
      y[((long)(b * 2048 + t)) * 2048 + h * 128 + dt * 16 + l16] = f2bf(O[dt][r] * inv[r]);
    }
}

extern "C" void kernel_launch(void* const* d_in, const int* in_sizes, int n_in,
                              void* d_out, int out_size, void* d_ws, size_t ws_size,
                              hipStream_t stream) {
  const float* x       = (const float*)d_in[0];
  const float* diag    = (const float*)d_in[1];
  const float* left_w  = (const float*)d_in[2];
  const float* right_w = (const float*)d_in[3];
  const float* right_b = (const float*)d_in[4];
  const float* bias_p  = (const float*)d_in[5];
  float* out = (float*)d_out;

  char* ws = (char*)d_ws;
  short* xb = (short*)(ws + 0);              // 33,554,432 B  (aliased as y after attention)
  short* LT = (short*)(ws + 33554432);       //  2,097,152 B
  short* WT = (short*)(ws + 35651584);       //  4,194,304 B
  short* xl = (short*)(ws + 39845888);       //  6,291,456 B
  short* yl = (short*)(ws + 46137344);       //  2,097,152 B
  short* qb = (short*)(ws + 48234496);       // 33,554,432 B
  short* kb = (short*)(ws + 81788928);       // 33,554,432 B
  short* vT = (short*)(ws + 115343360);      // 33,554,432 B  (end: 148,897,792)
  short* y  = xb;

  cast_x_kernel<<<16384, 256, 0, stream>>>(x, xb, 4194304L);
  prep_kernel<<<12288, 256, 0, stream>>>(left_w, diag, right_w, LT, WT);
  // xl[8192][384] = xb @ LT[0:384]^T
  gemm_bt<<<dim3(64, 3), 256, 0, stream>>>(xb, LT, xl, 8192, 384, 2048);
  // q,k,v
  lori_gemm<<<dim3(64, 48), 256, 0, stream>>>(xb, xl, 384, WT, right_b, bias_p, 0, qb, kb, vT, nullptr);
  // attention -> y (aliases xb)
  attn_kernel<<<dim3(32, 64), 256, 0, stream>>>(qb, kb, vT, y);
  // yl[8192][128] = y @ LT[384:512]^T
  gemm_bt<<<dim3(64, 1), 256, 0, stream>>>(y, LT + 3L * 128 * 2048, yl, 8192, 128, 2048);
  // final lori_fc -> fp32 out
  lori_gemm<<<dim3(64, 16), 256, 0, stream>>>(y, yl, 128, WT, right_b, bias_p, 3, nullptr, nullptr, nullptr, out);
}